// Round 13
// baseline (10842.825 us; speedup 1.0000x reference)
//
#include <hip/hip_runtime.h>
#include <hip/hip_bf16.h>
#include <math.h>

namespace {

constexpr int B = 256, S = 64, H = 768, L = 12, NH = 12, F = 3072, T = 11;
constexpr int BS = B * S;   // 16384 rows
constexpr int RC = 8192;    // rows per FFN chunk
constexpr int NCH = BS / RC;

typedef __attribute__((ext_vector_type(8))) short short8;
typedef __attribute__((ext_vector_type(4))) float f32x4;

__device__ __forceinline__ float gelu_tanh(float v) {
  float u = 0.7978845608028654f * (v + 0.044715f * v * v * v);
  u = fminf(fmaxf(u, -10.f), 10.f);
  float t = __expf(2.f * u);
  return 0.5f * v * (1.0f + (t - 1.f) / (t + 1.f));
}

// RNE float->bf16
__device__ __forceinline__ ushort f2bf(float v) {
  union { float f; unsigned u; } c; c.f = v;
  unsigned r = (c.u + 0x7fffu + ((c.u >> 16) & 1u)) >> 16;
  return (ushort)r;
}
__device__ __forceinline__ float bf2f(ushort u) {
  union { unsigned u; float f; } c; c.u = ((unsigned)u) << 16;
  return c.f;
}
__device__ __forceinline__ void split2(float v, ushort& hi, ushort& lo) {
  hi = f2bf(v);
  lo = f2bf(v - bf2f(hi));
}
__device__ __forceinline__ float join2(ushort hi, ushort lo) {
  return bf2f(hi) + bf2f(lo);
}
__device__ __forceinline__ float join2s(short hi, short lo) {
  return join2((ushort)hi, (ushort)lo);
}
// planar index of column c within a row (ushort offset): hi at ret, lo at ret+32
__device__ __forceinline__ int pcol(int c) { return ((c >> 5) << 6) + (c & 31); }

#define GLOAD_LDS16(gptr, ldsptr)                                                        \
  __builtin_amdgcn_global_load_lds((const __attribute__((address_space(1))) void*)(gptr), \
                                   (__attribute__((address_space(3))) void*)(ldsptr), 16, 0, 0)

// ============ 128x128 4-wave m97-style single-buffer GEMM, 3 blocks/CU ============
// (r11 operating point: MfmaUtil ~45%, ~1018 TF raw, 72 VGPR + 64 acc, no spill.)
// r13 change: COLUMN-major within-XCD block mapping -> concurrent blocks on one
// XCD share a single B panel (L2-resident) and stream A from L3 (FETCH 186->~70MB).
template <int MODE>
__global__ __launch_bounds__(256, 3) void gemm_mfma(const ushort* __restrict__ A,
                                                    const ushort* __restrict__ Bw,
                                                    const float* __restrict__ bias,
                                                    float* __restrict__ outF,
                                                    ushort* __restrict__ outU,
                                                    int lda2, int ldb2, int ldc2,
                                                    int ldcF, int zStrideF, int ktiles) {
  __shared__ ushort sA[128 * 64];   // [row][64 bf16] 128B rows (16KB)
  __shared__ ushort sB[128 * 64];
  const int tid = threadIdx.x;
  const int w = tid >> 6;       // 0..3
  const int lane = tid & 63;
  const int wm = w >> 1;        // 0..1
  const int wn = w & 1;         // 0..1

  // bijective XCD swizzle (all grid totals % 8 == 0), column-major decomposition:
  // consecutive swz on one XCD walk ROWS (by) with bx fixed -> B panel stays in L2.
  const int gx = gridDim.x, gy = gridDim.y;
  const int flat = ((int)blockIdx.z * gy + blockIdx.y) * gx + blockIdx.x;
  const int q8 = (gx * gy * (int)gridDim.z) >> 3;
  const int swz = (flat & 7) * q8 + (flat >> 3);
  const int by = swz % gy;
  const int bx = (swz / gy) % gx;
  const int bz = swz / (gx * gy);
  const int bm = by * 128;
  const int bn = bx * 128;
  const int k0 = bz * ktiles * 64;   // ushort elements

  // staging: per 8-row/1KB DMA chunk, lane l -> row +(l>>3), phys 16B-block l&7
  // sourced from logical block (l&7)^(l>>3)  (XOR swizzle, matched on read side)
  const int srow = lane >> 3;
  const int sblk = (lane & 7) ^ srow;
  const ushort* Ab = A + (size_t)(bm + w * 32 + srow) * lda2 + k0 + sblk * 8;
  const ushort* Bb = Bw + (size_t)(bn + w * 32 + srow) * ldb2 + k0 + sblk * 8;

  // fragment read constants (16x16x32: row = lane&15, k = 8*(lane>>4)+0..7)
  const int fr = lane & 15;
  const int s7 = fr & 7;
  const int jb = lane >> 4;                 // 0..3
  const int hOff = (jb ^ s7) << 3;          // hi: logical blocks 0..3
  const int lOff = ((4 + jb) ^ s7) << 3;    // lo: logical blocks 4..7

  f32x4 acc[4][4] = {};
  const int NT = ktiles;

  for (int t = 0; t < NT; ++t) {
#pragma unroll
    for (int c = 0; c < 4; ++c) {
      GLOAD_LDS16(Ab + (size_t)t * 64 + (size_t)(c * 8) * lda2, &sA[(w * 32 + c * 8) * 64]);
      GLOAD_LDS16(Bb + (size_t)t * 64 + (size_t)(c * 8) * ldb2, &sB[(w * 32 + c * 8) * 64]);
    }
    __syncthreads();  // drains vmcnt(0): tile data ready for all waves

    short8 bh[4], bl[4];
#pragma unroll
    for (int ni = 0; ni < 4; ++ni) {
      const ushort* baseB = &sB[(wn * 64 + ni * 16 + fr) * 64];
      bh[ni] = *(const short8*)(baseB + hOff);
      bl[ni] = *(const short8*)(baseB + lOff);
    }
    __builtin_amdgcn_s_setprio(1);
#pragma unroll
    for (int mi = 0; mi < 4; ++mi) {
      const ushort* baseA = &sA[(wm * 64 + mi * 16 + fr) * 64];
      short8 ah = *(const short8*)(baseA + hOff);
      short8 al = *(const short8*)(baseA + lOff);
#pragma unroll
      for (int ni = 0; ni < 4; ++ni) {
        acc[mi][ni] = __builtin_amdgcn_mfma_f32_16x16x32_bf16(ah, bh[ni], acc[mi][ni], 0, 0, 0);
        acc[mi][ni] = __builtin_amdgcn_mfma_f32_16x16x32_bf16(ah, bl[ni], acc[mi][ni], 0, 0, 0);
        acc[mi][ni] = __builtin_amdgcn_mfma_f32_16x16x32_bf16(al, bh[ni], acc[mi][ni], 0, 0, 0);
      }
    }
    __builtin_amdgcn_s_setprio(0);
    __syncthreads();  // all reads done before next-tile DMA overwrites
  }

  const int erow = jb << 2;  // C/D: col=lane&15, row=(lane>>4)*4+e
#pragma unroll
  for (int ni = 0; ni < 4; ++ni) {
    const int col = bn + wn * 64 + ni * 16 + fr;
    const float bv = (MODE == 3) ? 0.f : bias[col];
    const int cb = pcol(col);
#pragma unroll
    for (int mi = 0; mi < 4; ++mi) {
#pragma unroll
      for (int e = 0; e < 4; ++e) {
        const int row = bm + wm * 64 + mi * 16 + erow + e;
        float v = acc[mi][ni][e] + bv;
        if (MODE == 1 || MODE == 2) {
          if (MODE == 1) v = gelu_tanh(v);
          ushort hi, lo;
          split2(v, hi, lo);
          outU[(size_t)row * ldc2 + cb] = hi;
          outU[(size_t)row * ldc2 + cb + 32] = lo;
        } else {
          outF[(size_t)bz * zStrideF + (size_t)row * ldcF + col] = v;
        }
      }
    }
  }
}

// All four layer weights fp32 -> planar block-interleaved bf16 [N][2K], ONE launch.
// Tiles: wQ 72x24=1728, wO 24x24=576, wF1 96x24=2304, wF2 24x96=2304 -> 6912 blocks.
__global__ __launch_bounds__(256) void convert_all_w(const float* __restrict__ w0,
                                                     const float* __restrict__ w1,
                                                     const float* __restrict__ w2,
                                                     const float* __restrict__ w3,
                                                     ushort* __restrict__ d0,
                                                     ushort* __restrict__ d1,
                                                     ushort* __restrict__ d2,
                                                     ushort* __restrict__ d3) {
  __shared__ float tile[32][33];
  int b = blockIdx.x;
  const float* W;
  ushort* D;
  int K, N, nbx;
  if (b < 1728)      { W = w0; D = d0; K = H; N = 3 * H; nbx = 72; }
  else if (b < 2304) { b -= 1728; W = w1; D = d1; K = H; N = H; nbx = 24; }
  else if (b < 4608) { b -= 2304; W = w2; D = d2; K = H; N = F; nbx = 96; }
  else               { b -= 4608; W = w3; D = d3; K = F; N = H; nbx = 24; }
  const int kb = (b / nbx) * 32, nb = (b % nbx) * 32;
  const int tr = threadIdx.x >> 5;
  const int tc = threadIdx.x & 31;
#pragma unroll
  for (int p = 0; p < 4; ++p) {
    int r = tr + p * 8;
    tile[r][tc] = W[(size_t)(kb + r) * N + nb + tc];
  }
  __syncthreads();
  const int kblk = kb >> 5;
#pragma unroll
  for (int p = 0; p < 4; ++p) {
    int n = tr + p * 8;
    float v = tile[tc][n];
    ushort hi, lo;
    split2(v, hi, lo);
    size_t o = (size_t)(nb + n) * (2 * K) + (size_t)kblk * 64 + tc;
    D[o] = hi;
    D[o + 32] = lo;
  }
}

// One block per (batch, head). qkv planar bf16 [row][4608]; output written
// IN PLACE into the Q-slot columns. Vectorized short8 loads (8-d groups).
__global__ __launch_bounds__(256) void attn_kernel(ushort* __restrict__ qkv,
                                                   const int* __restrict__ mask) {
  __shared__ float smem[64 * 64 + 64 * 66 + 64 * 64];  // Qs | KsT | Vs ; Ps aliases
  float (*Qs)[64] = (float (*)[64])smem;
  float (*KsT)[66] = (float (*)[66])(smem + 64 * 64);
  float (*Vs)[64] = (float (*)[64])(smem + 64 * 64 + 64 * 66);
  float (*Ps)[65] = (float (*)[65])smem;

  const int bl = blockIdx.x / NH;
  const int hh = blockIdx.x % NH;
  const int tid = threadIdx.x;
  const int lane = tid & 63;
  const int w = tid >> 6;

  // 64 rows x 8 d-groups of 8 = 512 items, 2 per thread; vector hi/lo loads
#pragma unroll
  for (int it = 0; it < 2; ++it) {
    int item = tid + it * 256;
    int r = item >> 3, gq = item & 7;
    size_t rowb = (size_t)(bl * 64 + r) * 4608;
    int off = hh * 128 + (gq >> 2) * 64 + (gq & 3) * 8;
    short8 qh = *(const short8*)(qkv + rowb + off);
    short8 ql = *(const short8*)(qkv + rowb + off + 32);
    short8 kh = *(const short8*)(qkv + rowb + 1536 + off);
    short8 kl = *(const short8*)(qkv + rowb + 1536 + off + 32);
    short8 vh = *(const short8*)(qkv + rowb + 3072 + off);
    short8 vl = *(const short8*)(qkv + rowb + 3072 + off + 32);
#pragma unroll
    for (int j = 0; j < 8; ++j) {
      int d = gq * 8 + j;
      Qs[r][d] = join2s(qh[j], ql[j]);
      KsT[d][r] = join2s(kh[j], kl[j]);
      Vs[r][d] = join2s(vh[j], vl[j]);
    }
  }
  __syncthreads();

  float sc[16];
#pragma unroll
  for (int i = 0; i < 16; ++i) sc[i] = 0.f;
  for (int d = 0; d < 64; ++d) {
    float kv = KsT[d][lane];
#pragma unroll
    for (int i = 0; i < 16; ++i) sc[i] += Qs[w + 4 * i][d] * kv;
  }
  __syncthreads();
  float biask = (1.0f - (float)mask[bl * S + lane]) * -1e9f;
#pragma unroll
  for (int i = 0; i < 16; ++i) Ps[w + 4 * i][lane] = sc[i] * 0.125f + biask;
  __syncthreads();

  if (tid < 64) {
    int qr = tid;
    float mx = -1e30f;
    for (int k = 0; k < 64; ++k) mx = fmaxf(mx, Ps[qr][k]);
    float sum = 0.f;
    for (int k = 0; k < 64; ++k) {
      float e = expf(Ps[qr][k] - mx);
      Ps[qr][k] = e;
      sum += e;
    }
    float inv = 1.0f / sum;
    for (int k = 0; k < 64; ++k) Ps[qr][k] *= inv;
  }
  __syncthreads();

  float o[16];
#pragma unroll
  for (int i = 0; i < 16; ++i) o[i] = 0.f;
  for (int k = 0; k < 64; ++k) {
    float vv = Vs[k][lane];
#pragma unroll
    for (int i = 0; i < 16; ++i) o[i] += Ps[w + 4 * i][k] * vv;
  }
  const int ooff = hh * 128 + pcol(lane);
#pragma unroll
  for (int i = 0; i < 16; ++i) {
    int qr = w + 4 * i;
    size_t rowb = (size_t)(bl * 64 + qr) * 4608;
    ushort hi, lo;
    split2(o[i], hi, lo);
    qkv[rowb + ooff] = hi;
    qkv[rowb + ooff + 32] = lo;
  }
}

__global__ __launch_bounds__(256) void embed_ln_kernel(const int* __restrict__ ids,
                                                       const float* __restrict__ we,
                                                       const float* __restrict__ pe,
                                                       const float* __restrict__ te,
                                                       const float* __restrict__ g,
                                                       const float* __restrict__ bta,
                                                       ushort* __restrict__ xhl) {
  __shared__ float buf[H];
  __shared__ float red[256];
  const int row = blockIdx.x;
  const int s = row % S;
  const int tid = threadIdx.x;
  const int id = ids[row];
  float local = 0.f;
  for (int i = tid; i < H; i += 256) {
    float v = we[(size_t)id * H + i] + pe[(size_t)s * H + i] + te[i];
    buf[i] = v;
    local += v;
  }
  red[tid] = local;
  __syncthreads();
  for (int st = 128; st > 0; st >>= 1) {
    if (tid < st) red[tid] += red[tid + st];
    __syncthreads();
  }
  float mean = red[0] * (1.0f / H);
  __syncthreads();
  float ls = 0.f;
  for (int i = tid; i < H; i += 256) {
    float d = buf[i] - mean;
    ls += d * d;
  }
  red[tid] = ls;
  __syncthreads();
  for (int st = 128; st > 0; st >>= 1) {
    if (tid < st) red[tid] += red[tid + st];
    __syncthreads();
  }
  float inv = 1.0f / sqrtf(red[0] * (1.0f / H) + 1e-12f);
  for (int i = tid; i < H; i += 256) {
    float o = (buf[i] - mean) * inv * g[i] + bta[i];
    int cb = pcol(i);
    ushort hi, lo;
    split2(o, hi, lo);
    xhl[(size_t)row * (2 * H) + cb] = hi;
    xhl[(size_t)row * (2 * H) + cb + 32] = lo;
  }
}

// xhl = planar(LayerNorm(join(xhl) + p0 [+ p1] + bias) * g + b)
// Vectorized: 96 lanes x 8 elems in registers; short8 hi/lo + float4 partial loads.
template <int NP>
__global__ __launch_bounds__(256) void add_ln_kernel(ushort* __restrict__ xhl,
                                                     const float* __restrict__ pz0,
                                                     const float* __restrict__ pz1,
                                                     int prs,
                                                     const float* __restrict__ biasv,
                                                     const float* __restrict__ g,
                                                     const float* __restrict__ bta) {
  __shared__ float red[256];
  const size_t row = blockIdx.x;
  const int tid = threadIdx.x;
  float v[8];
  float local = 0.f;
  const int gq = tid;            // group covers cols gq*8 .. gq*8+7
  const int c0 = gq * 8;
  ushort* base = xhl + row * (2 * H) + (gq >> 2) * 64 + (gq & 3) * 8;
  if (tid < 96) {
    short8 hi = *(const short8*)(base);
    short8 lo = *(const short8*)(base + 32);
    f32x4 p0a = *(const f32x4*)(pz0 + row * (size_t)prs + c0);
    f32x4 p0b = *(const f32x4*)(pz0 + row * (size_t)prs + c0 + 4);
    f32x4 ba = *(const f32x4*)(biasv + c0);
    f32x4 bb = *(const f32x4*)(biasv + c0 + 4);
#pragma unroll
    for (int j = 0; j < 4; ++j) {
      v[j] = join2s(hi[j], lo[j]) + (p0a[j] + ba[j]);
      v[4 + j] = join2s(hi[4 + j], lo[4 + j]) + (p0b[j] + bb[j]);
    }
    if (NP == 2) {
      f32x4 p1a = *(const f32x4*)(pz1 + row * (size_t)prs + c0);
      f32x4 p1b = *(const f32x4*)(pz1 + row * (size_t)prs + c0 + 4);
#pragma unroll
      for (int j = 0; j < 4; ++j) {
        v[j] += p1a[j];
        v[4 + j] += p1b[j];
      }
    }
#pragma unroll
    for (int j = 0; j < 8; ++j) local += v[j];
  }
  red[tid] = local;
  __syncthreads();
  for (int st = 128; st > 0; st >>= 1) {
    if (tid < st) red[tid] += red[tid + st];
    __syncthreads();
  }
  float mean = red[0] * (1.0f / H);
  __syncthreads();
  float ls = 0.f;
  if (tid < 96) {
#pragma unroll
    for (int j = 0; j < 8; ++j) {
      float d = v[j] - mean;
      ls += d * d;
    }
  }
  red[tid] = ls;
  __syncthreads();
  for (int st = 128; st > 0; st >>= 1) {
    if (tid < st) red[tid] += red[tid + st];
    __syncthreads();
  }
  float inv = 1.0f / sqrtf(red[0] * (1.0f / H) + 1e-12f);
  if (tid < 96) {
    f32x4 ga = *(const f32x4*)(g + c0);
    f32x4 gb = *(const f32x4*)(g + c0 + 4);
    f32x4 ta = *(const f32x4*)(bta + c0);
    f32x4 tb = *(const f32x4*)(bta + c0 + 4);
    short8 ho, lo8;
#pragma unroll
    for (int j = 0; j < 4; ++j) {
      float o = (v[j] - mean) * inv * ga[j] + ta[j];
      ushort hi, lo;
      split2(o, hi, lo);
      ho[j] = (short)hi; lo8[j] = (short)lo;
      o = (v[4 + j] - mean) * inv * gb[j] + tb[j];
      split2(o, hi, lo);
      ho[4 + j] = (short)hi; lo8[4 + j] = (short)lo;
    }
    *(short8*)(base) = ho;
    *(short8*)(base + 32) = lo8;
  }
}

__global__ __launch_bounds__(256) void fc_kernel(const ushort* __restrict__ xhl,
                                                 const float* __restrict__ w,
                                                 const float* __restrict__ bias,
                                                 float* __restrict__ logits) {
  __shared__ float xs[H];
  const size_t row = blockIdx.x;
  const int tid = threadIdx.x;
  if (tid < 96) {
    const ushort* base = xhl + row * (2 * H) + (tid >> 2) * 64 + (tid & 3) * 8;
    short8 hi = *(const short8*)(base);
    short8 lo = *(const short8*)(base + 32);
#pragma unroll
    for (int j = 0; j < 8; ++j) xs[tid * 8 + j] = join2s(hi[j], lo[j]);
  }
  __syncthreads();
  const int j = tid >> 4, l = tid & 15;
  if (j < T) {
    float s = 0.f;
    for (int k = l; k < H; k += 16) s += xs[k] * w[(size_t)k * T + j];
#pragma unroll
    for (int d = 8; d > 0; d >>= 1) s += __shfl_down(s, d, 16);
    if (l == 0) logits[row * T + j] = s + bias[j];
  }
}

__global__ __launch_bounds__(64) void crf_llh_kernel(const float* __restrict__ em,
                                                     const int* __restrict__ label,
                                                     const int* __restrict__ mask,
                                                     const float* __restrict__ start,
                                                     const float* __restrict__ endw,
                                                     const float* __restrict__ trans,
                                                     float* __restrict__ llh) {
  const int b = blockIdx.x;
  const int c = threadIdx.x;
  __shared__ float alpha[T];
  __shared__ float tr[T][T];
  for (int i = c; i < T * T; i += 64) tr[i / T][i % T] = trans[i];
  if (c < T) alpha[c] = start[c] + em[(size_t)b * S * T + c];
  __syncthreads();
  for (int s = 1; s < S; ++s) {
    float a = 0.f;
    if (c < T) {
      float mx = -1e30f;
      for (int p = 0; p < T; ++p) mx = fmaxf(mx, alpha[p] + tr[p][c]);
      float sum = 0.f;
      for (int p = 0; p < T; ++p) sum += expf(alpha[p] + tr[p][c] - mx);
      a = mx + logf(sum) + em[((size_t)b * S + s) * T + c];
    }
    __syncthreads();
    if (c < T) {
      float m = (float)mask[b * S + s];
      alpha[c] = (m > 0.f) ? a : alpha[c];
    }
    __syncthreads();
  }
  if (c == 0) {
    float mx = -1e30f;
    for (int p = 0; p < T; ++p) mx = fmaxf(mx, alpha[p] + endw[p]);
    float sum = 0.f;
    for (int p = 0; p < T; ++p) sum += expf(alpha[p] + endw[p] - mx);
    float denom = mx + logf(sum);

    int t0 = label[b * S];
    float score = start[t0] + em[(size_t)b * S * T + t0];
    int prev = t0;
    for (int s = 1; s < S; ++s) {
      int tc = label[b * S + s];
      float m = (float)mask[b * S + s];
      score += (tr[prev][tc] + em[((size_t)b * S + s) * T + tc]) * m;
      prev = tc;
    }
    int msum = 0;
    for (int s = 0; s < S; ++s) msum += mask[b * S + s];
    score += endw[label[b * S + (msum - 1)]];
    llh[b] = score - denom;
  }
}

__global__ __launch_bounds__(256) void loss_kernel(const float* __restrict__ llh,
                                                   float* __restrict__ out) {
  __shared__ float red[256];
  const int tid = threadIdx.x;
  red[tid] = llh[tid];  // B == 256
  __syncthreads();
  for (int st = 128; st > 0; st >>= 1) {
    if (tid < st) red[tid] += red[tid + st];
    __syncthreads();
  }
  if (tid == 0) out[BS] = -red[0] * (1.0f / B);
}

__global__ __launch_bounds__(64) void viterbi_kernel(const float* __restrict__ em,
                                                     const int* __restrict__ mask,
                                                     const float* __restrict__ start,
                                                     const float* __restrict__ endw,
                                                     const float* __restrict__ trans,
                                                     float* __restrict__ pred) {
  const int b = blockIdx.x;
  const int c = threadIdx.x;
  __shared__ float sc[T];
  __shared__ float tr[T][T];
  __shared__ int hist[S - 1][T];
  for (int i = c; i < T * T; i += 64) tr[i / T][i % T] = trans[i];
  if (c < T) sc[c] = start[c] + em[(size_t)b * S * T + c];
  __syncthreads();
  for (int s = 1; s < S; ++s) {
    float bestv = -1e30f;
    int bestp = 0;
    if (c < T) {
      for (int p = 0; p < T; ++p) {
        float v = sc[p] + tr[p][c];
        if (v > bestv) { bestv = v; bestp = p; }
      }
      hist[s - 1][c] = bestp;
    }
    __syncthreads();
    if (c < T) {
      float m = (float)mask[b * S + s];
      sc[c] = (m > 0.f) ? (bestv + em[((size_t)b * S + s) * T + c]) : sc[c];
    }
    __syncthreads();
  }
  if (c == 0) {
    float bv = -1e30f;
    int last = 0;
    for (int p = 0; p < T; ++p) {
      float v = sc[p] + endw[p];
      if (v > bv) { bv = v; last = p; }
    }
    pred[b * S + (S - 1)] = (float)last;
    int t = last;
    for (int hs = S - 2; hs >= 0; --hs) {
      if (mask[b * S + hs + 1] > 0) t = hist[hs][t];
      pred[b * S + hs] = (float)t;
    }
  }
}

}  // namespace

extern "C" void kernel_launch(void* const* d_in, const int* in_sizes, int n_in,
                              void* d_out, int out_size, void* d_ws, size_t ws_size,
                              hipStream_t stream) {
  (void)in_sizes; (void)n_in; (void)out_size; (void)ws_size;
  const int* input_ids = (const int*)d_in[0];
  const int* attn_mask = (const int*)d_in[1];
  const int* label = (const int*)d_in[2];
  const float* word_emb = (const float*)d_in[3];
  const float* pos_emb = (const float*)d_in[4];
  const float* tok_emb = (const float*)d_in[5];
  const float* eg = (const float*)d_in[6];
  const float* ebt = (const float*)d_in[7];
  const float* Wqkv = (const float*)d_in[8];
  const float* bqkv = (const float*)d_in[9];
  const float* Wo = (const float*)d_in[10];
  const float* bo = (const float*)d_in[11];
  const float* ln1g = (const float*)d_in[12];
  const float* ln1b = (const float*)d_in[13];
  const float* W1 = (const float*)d_in[14];
  const float* b1 = (const float*)d_in[15];
  const float* W2 = (const float*)d_in[16];
  const float* b2 = (const float*)d_in[17];
  const float* ln2g = (const float*)d_in[18];
  const float* ln2b = (const float*)d_in[19];
  const float* fc_w = (const float*)d_in[20];
  const float* fc_b = (const float*)d_in[21];
  const float* crf_start = (const float*)d_in[22];
  const float* crf_end = (const float*)d_in[23];
  const float* crf_trans = (const float*)d_in[24];
  float* out = (float*)d_out;

  // ---- workspace layout (~231 MB, proven footprint) ----
  char* p = (char*)d_ws;
  ushort* xhl = (ushort*)p;    p += (size_t)BS * 2 * H * 2;      // planar residual [BS][1536]
  ushort* wQ = (ushort*)p;     p += (size_t)3 * H * 2 * H * 2;   // [2304][1536]
  ushort* wO = (ushort*)p;     p += (size_t)H * 2 * H * 2;       // [768][1536]
  ushort* wF1 = (ushort*)p;    p += (size_t)F * 2 * H * 2;       // [3072][1536]
  ushort* wF2 = (ushort*)p;    p += (size_t)H * 2 * F * 2;       // [768][6144]
  char* big = p;               p += (size_t)BS * 3 * H * 4;      // 151 MB
  float* logits = (float*)p;   p += (size_t)BS * T * 4;
  float* llh = (float*)p;      p += (size_t)B * 4;
  ushort* qkvP = (ushort*)big;             // [BS][4608] planar; attn out -> Q slot
  float* qf = (float*)big;                 // f32 row view [BS][2304]; Wo partial in K slot
  ushort* hU = (ushort*)big;               // [RC][6144] planar (FFN phase)
  float* pf = (float*)(big + (size_t)RC * F * 4);  // [2][RC][H] fp32 FFN2 partials

  embed_ln_kernel<<<BS, 256, 0, stream>>>(input_ids, word_emb, pos_emb, tok_emb, eg, ebt, xhl);

  for (int l = 0; l < L; ++l) {
    const float* wqkv_l = Wqkv + (size_t)l * H * 3 * H;
    const float* bqkv_l = bqkv + (size_t)l * 3 * H;
    const float* wo_l = Wo + (size_t)l * H * H;
    const float* bo_l = bo + (size_t)l * H;
    const float* g1 = ln1g + (size_t)l * H;
    const float* be1 = ln1b + (size_t)l * H;
    const float* w1_l = W1 + (size_t)l * H * F;
    const float* b1_l = b1 + (size_t)l * F;
    const float* w2_l = W2 + (size_t)l * F * H;
    const float* b2_l = b2 + (size_t)l * H;
    const float* g2 = ln2g + (size_t)l * H;
    const float* be2 = ln2b + (size_t)l * H;

    // all 4 weight conversions in ONE launch (6912 blocks)
    convert_all_w<<<6912, 256, 0, stream>>>(wqkv_l, wo_l, w1_l, w2_l, wQ, wO, wF1, wF2);

    // ---- attention block ----
    // QKV: [BS,H] @ [H,3H] -> qkvP planar.  grid 18x128 = 2304
    gemm_mfma<2><<<dim3(3 * H / 128, BS / 128, 1), 256, 0, stream>>>(
        xhl, wQ, bqkv_l, nullptr, qkvP, 2 * H, 2 * H, 2 * 3 * H, 0, 0, H / 32);
    attn_kernel<<<B * NH, 256, 0, stream>>>(qkvP, attn_mask);
    // Wo: [BS,H(Q-slot)] @ [H,H] -> fp32 into dead K slot, z=1 (full K per block).
    gemm_mfma<3><<<dim3(H / 128, BS / 128, 1), 256, 0, stream>>>(
        qkvP, wO, nullptr, qf + H, nullptr, 2 * 3 * H, 2 * H, 0, 3 * H, 0, H / 32);
    add_ln_kernel<1><<<BS, 256, 0, stream>>>(xhl, qf + H, nullptr, 3 * H, bo_l, g1, be1);

    // ---- FFN block (chunked) ----
    for (int ch = 0; ch < NCH; ++ch) {
      // FFN1: [RC,H] @ [H,F] -> hU (gelu, planar).  grid 24x64 = 1536
      gemm_mfma<1><<<dim3(F / 128, RC / 128, 1), 256, 0, stream>>>(
          xhl + (size_t)ch * RC * 2 * H, wF1, b1_l, nullptr, hU, 2 * H, 2 * H, 2 * F,
          0, 0, H / 32);
      // FFN2: [RC,F] @ [F,H] -> fp32 partials pf (z=2).  grid 6x64x2 = 768
      gemm_mfma<3><<<dim3(H / 128, RC / 128, 2), 256, 0, stream>>>(
          hU, wF2, nullptr, pf, nullptr, 2 * F, 2 * F, 0, H, RC * H, F / 64);
      add_ln_kernel<2><<<RC, 256, 0, stream>>>(xhl + (size_t)ch * RC * 2 * H, pf,
                                               pf + (size_t)RC * H, H, b2_l, g2, be2);
    }
  }

  fc_kernel<<<BS, 256, 0, stream>>>(xhl, fc_w, fc_b, logits);
  crf_llh_kernel<<<B, 64, 0, stream>>>(logits, label, attn_mask, crf_start, crf_end, crf_trans, llh);
  loss_kernel<<<1, 256, 0, stream>>>(llh, out);
  viterbi_kernel<<<B, 64, 0, stream>>>(logits, attn_mask, crf_start, crf_end, crf_trans, out);
}

// Round 14
// 10148.583 us; speedup vs baseline: 1.0684x; 1.0684x over previous
//
#include <hip/hip_runtime.h>
#include <hip/hip_bf16.h>
#include <math.h>

namespace {

constexpr int B = 256, S = 64, H = 768, L = 12, NH = 12, F = 3072, T = 11;
constexpr int BS = B * S;   // 16384 rows
constexpr int RC = 8192;    // rows per FFN chunk
constexpr int NCH = BS / RC;

typedef __attribute__((ext_vector_type(8))) short short8;
typedef __attribute__((ext_vector_type(4))) float f32x4;

__device__ __forceinline__ float gelu_tanh(float v) {
  float u = 0.7978845608028654f * (v + 0.044715f * v * v * v);
  u = fminf(fmaxf(u, -10.f), 10.f);
  float t = __expf(2.f * u);
  return 0.5f * v * (1.0f + (t - 1.f) / (t + 1.f));
}

// RNE float->bf16
__device__ __forceinline__ ushort f2bf(float v) {
  union { float f; unsigned u; } c; c.f = v;
  unsigned r = (c.u + 0x7fffu + ((c.u >> 16) & 1u)) >> 16;
  return (ushort)r;
}
__device__ __forceinline__ float bf2f(ushort u) {
  union { unsigned u; float f; } c; c.u = ((unsigned)u) << 16;
  return c.f;
}
__device__ __forceinline__ void split2(float v, ushort& hi, ushort& lo) {
  hi = f2bf(v);
  lo = f2bf(v - bf2f(hi));
}
__device__ __forceinline__ float join2(ushort hi, ushort lo) {
  return bf2f(hi) + bf2f(lo);
}
__device__ __forceinline__ float join2s(short hi, short lo) {
  return join2((ushort)hi, (ushort)lo);
}
// planar index of column c within a row (ushort offset): hi at ret, lo at ret+32
__device__ __forceinline__ int pcol(int c) { return ((c >> 5) << 6) + (c & 31); }

#define GLOAD_LDS16(gptr, ldsptr)                                                        \
  __builtin_amdgcn_global_load_lds((const __attribute__((address_space(1))) void*)(gptr), \
                                   (__attribute__((address_space(3))) void*)(ldsptr), 16, 0, 0)

// ============ 128x128 4-wave m97-style single-buffer GEMM, 3 blocks/CU ============
// r12-verbatim (proven 10.21ms operating point: MfmaUtil ~44%, ~1018 TF, no spill).
// Row-major in-XCD block mapping: caches the LARGE A panels in L2, lets the small
// B thrash (r13's column-major inverted this and cost 2.4x FETCH -> reverted).
template <int MODE>
__global__ __launch_bounds__(256, 3) void gemm_mfma(const ushort* __restrict__ A,
                                                    const ushort* __restrict__ Bw,
                                                    const float* __restrict__ bias,
                                                    float* __restrict__ outF,
                                                    ushort* __restrict__ outU,
                                                    int lda2, int ldb2, int ldc2,
                                                    int ldcF, int zStrideF, int ktiles) {
  __shared__ ushort sA[128 * 64];   // [row][64 bf16] 128B rows (16KB)
  __shared__ ushort sB[128 * 64];
  const int tid = threadIdx.x;
  const int w = tid >> 6;       // 0..3
  const int lane = tid & 63;
  const int wm = w >> 1;        // 0..1
  const int wn = w & 1;         // 0..1

  // bijective XCD swizzle over the whole grid (all totals % 8 == 0)
  const int gx = gridDim.x, gy = gridDim.y;
  const int flat = ((int)blockIdx.z * gy + blockIdx.y) * gx + blockIdx.x;
  const int q8 = (gx * gy * (int)gridDim.z) >> 3;
  const int swz = (flat & 7) * q8 + (flat >> 3);
  const int bx = swz % gx;
  const int by = (swz / gx) % gy;
  const int bz = swz / (gx * gy);
  const int bm = by * 128;
  const int bn = bx * 128;
  const int k0 = bz * ktiles * 64;   // ushort elements

  // staging: per 8-row/1KB DMA chunk, lane l -> row +(l>>3), phys 16B-block l&7
  // sourced from logical block (l&7)^(l>>3)  (XOR swizzle, matched on read side)
  const int srow = lane >> 3;
  const int sblk = (lane & 7) ^ srow;
  const ushort* Ab = A + (size_t)(bm + w * 32 + srow) * lda2 + k0 + sblk * 8;
  const ushort* Bb = Bw + (size_t)(bn + w * 32 + srow) * ldb2 + k0 + sblk * 8;

  // fragment read constants (16x16x32: row = lane&15, k = 8*(lane>>4)+0..7)
  const int fr = lane & 15;
  const int s7 = fr & 7;
  const int jb = lane >> 4;                 // 0..3
  const int hOff = (jb ^ s7) << 3;          // hi: logical blocks 0..3
  const int lOff = ((4 + jb) ^ s7) << 3;    // lo: logical blocks 4..7

  f32x4 acc[4][4] = {};
  const int NT = ktiles;

  for (int t = 0; t < NT; ++t) {
#pragma unroll
    for (int c = 0; c < 4; ++c) {
      GLOAD_LDS16(Ab + (size_t)t * 64 + (size_t)(c * 8) * lda2, &sA[(w * 32 + c * 8) * 64]);
      GLOAD_LDS16(Bb + (size_t)t * 64 + (size_t)(c * 8) * ldb2, &sB[(w * 32 + c * 8) * 64]);
    }
    __syncthreads();  // drains vmcnt(0): tile data ready for all waves

    short8 bh[4], bl[4];
#pragma unroll
    for (int ni = 0; ni < 4; ++ni) {
      const ushort* baseB = &sB[(wn * 64 + ni * 16 + fr) * 64];
      bh[ni] = *(const short8*)(baseB + hOff);
      bl[ni] = *(const short8*)(baseB + lOff);
    }
    __builtin_amdgcn_s_setprio(1);
#pragma unroll
    for (int mi = 0; mi < 4; ++mi) {
      const ushort* baseA = &sA[(wm * 64 + mi * 16 + fr) * 64];
      short8 ah = *(const short8*)(baseA + hOff);
      short8 al = *(const short8*)(baseA + lOff);
#pragma unroll
      for (int ni = 0; ni < 4; ++ni) {
        acc[mi][ni] = __builtin_amdgcn_mfma_f32_16x16x32_bf16(ah, bh[ni], acc[mi][ni], 0, 0, 0);
        acc[mi][ni] = __builtin_amdgcn_mfma_f32_16x16x32_bf16(ah, bl[ni], acc[mi][ni], 0, 0, 0);
        acc[mi][ni] = __builtin_amdgcn_mfma_f32_16x16x32_bf16(al, bh[ni], acc[mi][ni], 0, 0, 0);
      }
    }
    __builtin_amdgcn_s_setprio(0);
    __syncthreads();  // all reads done before next-tile DMA overwrites
  }

  const int erow = jb << 2;  // C/D: col=lane&15, row=(lane>>4)*4+e
#pragma unroll
  for (int ni = 0; ni < 4; ++ni) {
    const int col = bn + wn * 64 + ni * 16 + fr;
    const float bv = (MODE == 3) ? 0.f : bias[col];
    const int cb = pcol(col);
#pragma unroll
    for (int mi = 0; mi < 4; ++mi) {
#pragma unroll
      for (int e = 0; e < 4; ++e) {
        const int row = bm + wm * 64 + mi * 16 + erow + e;
        float v = acc[mi][ni][e] + bv;
        if (MODE == 1 || MODE == 2) {
          if (MODE == 1) v = gelu_tanh(v);
          ushort hi, lo;
          split2(v, hi, lo);
          outU[(size_t)row * ldc2 + cb] = hi;
          outU[(size_t)row * ldc2 + cb + 32] = lo;
        } else {
          outF[(size_t)bz * zStrideF + (size_t)row * ldcF + col] = v;
        }
      }
    }
  }
}

// All four layer weights fp32 -> planar block-interleaved bf16 [N][2K], ONE launch.
// Tiles: wQ 72x24=1728, wO 24x24=576, wF1 96x24=2304, wF2 24x96=2304 -> 6912 blocks.
__global__ __launch_bounds__(256) void convert_all_w(const float* __restrict__ w0,
                                                     const float* __restrict__ w1,
                                                     const float* __restrict__ w2,
                                                     const float* __restrict__ w3,
                                                     ushort* __restrict__ d0,
                                                     ushort* __restrict__ d1,
                                                     ushort* __restrict__ d2,
                                                     ushort* __restrict__ d3) {
  __shared__ float tile[32][33];
  int b = blockIdx.x;
  const float* W;
  ushort* D;
  int K, N, nbx;
  if (b < 1728)      { W = w0; D = d0; K = H; N = 3 * H; nbx = 72; }
  else if (b < 2304) { b -= 1728; W = w1; D = d1; K = H; N = H; nbx = 24; }
  else if (b < 4608) { b -= 2304; W = w2; D = d2; K = H; N = F; nbx = 96; }
  else               { b -= 4608; W = w3; D = d3; K = F; N = H; nbx = 24; }
  const int kb = (b / nbx) * 32, nb = (b % nbx) * 32;
  const int tr = threadIdx.x >> 5;
  const int tc = threadIdx.x & 31;
#pragma unroll
  for (int p = 0; p < 4; ++p) {
    int r = tr + p * 8;
    tile[r][tc] = W[(size_t)(kb + r) * N + nb + tc];
  }
  __syncthreads();
  const int kblk = kb >> 5;
#pragma unroll
  for (int p = 0; p < 4; ++p) {
    int n = tr + p * 8;
    float v = tile[tc][n];
    ushort hi, lo;
    split2(v, hi, lo);
    size_t o = (size_t)(nb + n) * (2 * K) + (size_t)kblk * 64 + tc;
    D[o] = hi;
    D[o + 32] = lo;
  }
}

// One block per (batch, head). qkv planar bf16 [row][4608]; output written
// IN PLACE into the Q-slot columns. Vectorized short8 loads (8-d groups).
__global__ __launch_bounds__(256) void attn_kernel(ushort* __restrict__ qkv,
                                                   const int* __restrict__ mask) {
  __shared__ float smem[64 * 64 + 64 * 66 + 64 * 64];  // Qs | KsT | Vs ; Ps aliases
  float (*Qs)[64] = (float (*)[64])smem;
  float (*KsT)[66] = (float (*)[66])(smem + 64 * 64);
  float (*Vs)[64] = (float (*)[64])(smem + 64 * 64 + 64 * 66);
  float (*Ps)[65] = (float (*)[65])smem;

  const int bl = blockIdx.x / NH;
  const int hh = blockIdx.x % NH;
  const int tid = threadIdx.x;
  const int lane = tid & 63;
  const int w = tid >> 6;

  // 64 rows x 8 d-groups of 8 = 512 items, 2 per thread; vector hi/lo loads
#pragma unroll
  for (int it = 0; it < 2; ++it) {
    int item = tid + it * 256;
    int r = item >> 3, gq = item & 7;
    size_t rowb = (size_t)(bl * 64 + r) * 4608;
    int off = hh * 128 + (gq >> 2) * 64 + (gq & 3) * 8;
    short8 qh = *(const short8*)(qkv + rowb + off);
    short8 ql = *(const short8*)(qkv + rowb + off + 32);
    short8 kh = *(const short8*)(qkv + rowb + 1536 + off);
    short8 kl = *(const short8*)(qkv + rowb + 1536 + off + 32);
    short8 vh = *(const short8*)(qkv + rowb + 3072 + off);
    short8 vl = *(const short8*)(qkv + rowb + 3072 + off + 32);
#pragma unroll
    for (int j = 0; j < 8; ++j) {
      int d = gq * 8 + j;
      Qs[r][d] = join2s(qh[j], ql[j]);
      KsT[d][r] = join2s(kh[j], kl[j]);
      Vs[r][d] = join2s(vh[j], vl[j]);
    }
  }
  __syncthreads();

  float sc[16];
#pragma unroll
  for (int i = 0; i < 16; ++i) sc[i] = 0.f;
  for (int d = 0; d < 64; ++d) {
    float kv = KsT[d][lane];
#pragma unroll
    for (int i = 0; i < 16; ++i) sc[i] += Qs[w + 4 * i][d] * kv;
  }
  __syncthreads();
  float biask = (1.0f - (float)mask[bl * S + lane]) * -1e9f;
#pragma unroll
  for (int i = 0; i < 16; ++i) Ps[w + 4 * i][lane] = sc[i] * 0.125f + biask;
  __syncthreads();

  if (tid < 64) {
    int qr = tid;
    float mx = -1e30f;
    for (int k = 0; k < 64; ++k) mx = fmaxf(mx, Ps[qr][k]);
    float sum = 0.f;
    for (int k = 0; k < 64; ++k) {
      float e = expf(Ps[qr][k] - mx);
      Ps[qr][k] = e;
      sum += e;
    }
    float inv = 1.0f / sum;
    for (int k = 0; k < 64; ++k) Ps[qr][k] *= inv;
  }
  __syncthreads();

  float o[16];
#pragma unroll
  for (int i = 0; i < 16; ++i) o[i] = 0.f;
  for (int k = 0; k < 64; ++k) {
    float vv = Vs[k][lane];
#pragma unroll
    for (int i = 0; i < 16; ++i) o[i] += Ps[w + 4 * i][k] * vv;
  }
  const int ooff = hh * 128 + pcol(lane);
#pragma unroll
  for (int i = 0; i < 16; ++i) {
    int qr = w + 4 * i;
    size_t rowb = (size_t)(bl * 64 + qr) * 4608;
    ushort hi, lo;
    split2(o[i], hi, lo);
    qkv[rowb + ooff] = hi;
    qkv[rowb + ooff + 32] = lo;
  }
}

__global__ __launch_bounds__(256) void embed_ln_kernel(const int* __restrict__ ids,
                                                       const float* __restrict__ we,
                                                       const float* __restrict__ pe,
                                                       const float* __restrict__ te,
                                                       const float* __restrict__ g,
                                                       const float* __restrict__ bta,
                                                       ushort* __restrict__ xhl) {
  __shared__ float buf[H];
  __shared__ float red[256];
  const int row = blockIdx.x;
  const int s = row % S;
  const int tid = threadIdx.x;
  const int id = ids[row];
  float local = 0.f;
  for (int i = tid; i < H; i += 256) {
    float v = we[(size_t)id * H + i] + pe[(size_t)s * H + i] + te[i];
    buf[i] = v;
    local += v;
  }
  red[tid] = local;
  __syncthreads();
  for (int st = 128; st > 0; st >>= 1) {
    if (tid < st) red[tid] += red[tid + st];
    __syncthreads();
  }
  float mean = red[0] * (1.0f / H);
  __syncthreads();
  float ls = 0.f;
  for (int i = tid; i < H; i += 256) {
    float d = buf[i] - mean;
    ls += d * d;
  }
  red[tid] = ls;
  __syncthreads();
  for (int st = 128; st > 0; st >>= 1) {
    if (tid < st) red[tid] += red[tid + st];
    __syncthreads();
  }
  float inv = 1.0f / sqrtf(red[0] * (1.0f / H) + 1e-12f);
  for (int i = tid; i < H; i += 256) {
    float o = (buf[i] - mean) * inv * g[i] + bta[i];
    int cb = pcol(i);
    ushort hi, lo;
    split2(o, hi, lo);
    xhl[(size_t)row * (2 * H) + cb] = hi;
    xhl[(size_t)row * (2 * H) + cb + 32] = lo;
  }
}

// xhl = planar(LayerNorm(join(xhl) + p0 [+ p1] + bias) * g + b)
// Vectorized: 96 lanes x 8 elems in registers; short8 hi/lo + float4 partial loads.
template <int NP>
__global__ __launch_bounds__(256) void add_ln_kernel(ushort* __restrict__ xhl,
                                                     const float* __restrict__ pz0,
                                                     const float* __restrict__ pz1,
                                                     int prs,
                                                     const float* __restrict__ biasv,
                                                     const float* __restrict__ g,
                                                     const float* __restrict__ bta) {
  __shared__ float red[256];
  const size_t row = blockIdx.x;
  const int tid = threadIdx.x;
  float v[8];
  float local = 0.f;
  const int gq = tid;            // group covers cols gq*8 .. gq*8+7
  const int c0 = gq * 8;
  ushort* base = xhl + row * (2 * H) + (gq >> 2) * 64 + (gq & 3) * 8;
  if (tid < 96) {
    short8 hi = *(const short8*)(base);
    short8 lo = *(const short8*)(base + 32);
    f32x4 p0a = *(const f32x4*)(pz0 + row * (size_t)prs + c0);
    f32x4 p0b = *(const f32x4*)(pz0 + row * (size_t)prs + c0 + 4);
    f32x4 ba = *(const f32x4*)(biasv + c0);
    f32x4 bb = *(const f32x4*)(biasv + c0 + 4);
#pragma unroll
    for (int j = 0; j < 4; ++j) {
      v[j] = join2s(hi[j], lo[j]) + (p0a[j] + ba[j]);
      v[4 + j] = join2s(hi[4 + j], lo[4 + j]) + (p0b[j] + bb[j]);
    }
    if (NP == 2) {
      f32x4 p1a = *(const f32x4*)(pz1 + row * (size_t)prs + c0);
      f32x4 p1b = *(const f32x4*)(pz1 + row * (size_t)prs + c0 + 4);
#pragma unroll
      for (int j = 0; j < 4; ++j) {
        v[j] += p1a[j];
        v[4 + j] += p1b[j];
      }
    }
#pragma unroll
    for (int j = 0; j < 8; ++j) local += v[j];
  }
  red[tid] = local;
  __syncthreads();
  for (int st = 128; st > 0; st >>= 1) {
    if (tid < st) red[tid] += red[tid + st];
    __syncthreads();
  }
  float mean = red[0] * (1.0f / H);
  __syncthreads();
  float ls = 0.f;
  if (tid < 96) {
#pragma unroll
    for (int j = 0; j < 8; ++j) {
      float d = v[j] - mean;
      ls += d * d;
    }
  }
  red[tid] = ls;
  __syncthreads();
  for (int st = 128; st > 0; st >>= 1) {
    if (tid < st) red[tid] += red[tid + st];
    __syncthreads();
  }
  float inv = 1.0f / sqrtf(red[0] * (1.0f / H) + 1e-12f);
  if (tid < 96) {
    f32x4 ga = *(const f32x4*)(g + c0);
    f32x4 gb = *(const f32x4*)(g + c0 + 4);
    f32x4 ta = *(const f32x4*)(bta + c0);
    f32x4 tb = *(const f32x4*)(bta + c0 + 4);
    short8 ho, lo8;
#pragma unroll
    for (int j = 0; j < 4; ++j) {
      float o = (v[j] - mean) * inv * ga[j] + ta[j];
      ushort hi, lo;
      split2(o, hi, lo);
      ho[j] = (short)hi; lo8[j] = (short)lo;
      o = (v[4 + j] - mean) * inv * gb[j] + tb[j];
      split2(o, hi, lo);
      ho[4 + j] = (short)hi; lo8[4 + j] = (short)lo;
    }
    *(short8*)(base) = ho;
    *(short8*)(base + 32) = lo8;
  }
}

__global__ __launch_bounds__(256) void fc_kernel(const ushort* __restrict__ xhl,
                                                 const float* __restrict__ w,
                                                 const float* __restrict__ bias,
                                                 float* __restrict__ logits) {
  __shared__ float xs[H];
  const size_t row = blockIdx.x;
  const int tid = threadIdx.x;
  if (tid < 96) {
    const ushort* base = xhl + row * (2 * H) + (tid >> 2) * 64 + (tid & 3) * 8;
    short8 hi = *(const short8*)(base);
    short8 lo = *(const short8*)(base + 32);
#pragma unroll
    for (int j = 0; j < 8; ++j) xs[tid * 8 + j] = join2s(hi[j], lo[j]);
  }
  __syncthreads();
  const int j = tid >> 4, l = tid & 15;
  if (j < T) {
    float s = 0.f;
    for (int k = l; k < H; k += 16) s += xs[k] * w[(size_t)k * T + j];
#pragma unroll
    for (int d = 8; d > 0; d >>= 1) s += __shfl_down(s, d, 16);
    if (l == 0) logits[row * T + j] = s + bias[j];
  }
}

__global__ __launch_bounds__(64) void crf_llh_kernel(const float* __restrict__ em,
                                                     const int* __restrict__ label,
                                                     const int* __restrict__ mask,
                                                     const float* __restrict__ start,
                                                     const float* __restrict__ endw,
                                                     const float* __restrict__ trans,
                                                     float* __restrict__ llh) {
  const int b = blockIdx.x;
  const int c = threadIdx.x;
  __shared__ float alpha[T];
  __shared__ float tr[T][T];
  for (int i = c; i < T * T; i += 64) tr[i / T][i % T] = trans[i];
  if (c < T) alpha[c] = start[c] + em[(size_t)b * S * T + c];
  __syncthreads();
  for (int s = 1; s < S; ++s) {
    float a = 0.f;
    if (c < T) {
      float mx = -1e30f;
      for (int p = 0; p < T; ++p) mx = fmaxf(mx, alpha[p] + tr[p][c]);
      float sum = 0.f;
      for (int p = 0; p < T; ++p) sum += expf(alpha[p] + tr[p][c] - mx);
      a = mx + logf(sum) + em[((size_t)b * S + s) * T + c];
    }
    __syncthreads();
    if (c < T) {
      float m = (float)mask[b * S + s];
      alpha[c] = (m > 0.f) ? a : alpha[c];
    }
    __syncthreads();
  }
  if (c == 0) {
    float mx = -1e30f;
    for (int p = 0; p < T; ++p) mx = fmaxf(mx, alpha[p] + endw[p]);
    float sum = 0.f;
    for (int p = 0; p < T; ++p) sum += expf(alpha[p] + endw[p] - mx);
    float denom = mx + logf(sum);

    int t0 = label[b * S];
    float score = start[t0] + em[(size_t)b * S * T + t0];
    int prev = t0;
    for (int s = 1; s < S; ++s) {
      int tc = label[b * S + s];
      float m = (float)mask[b * S + s];
      score += (tr[prev][tc] + em[((size_t)b * S + s) * T + tc]) * m;
      prev = tc;
    }
    int msum = 0;
    for (int s = 0; s < S; ++s) msum += mask[b * S + s];
    score += endw[label[b * S + (msum - 1)]];
    llh[b] = score - denom;
  }
}

__global__ __launch_bounds__(256) void loss_kernel(const float* __restrict__ llh,
                                                   float* __restrict__ out) {
  __shared__ float red[256];
  const int tid = threadIdx.x;
  red[tid] = llh[tid];  // B == 256
  __syncthreads();
  for (int st = 128; st > 0; st >>= 1) {
    if (tid < st) red[tid] += red[tid + st];
    __syncthreads();
  }
  if (tid == 0) out[BS] = -red[0] * (1.0f / B);
}

__global__ __launch_bounds__(64) void viterbi_kernel(const float* __restrict__ em,
                                                     const int* __restrict__ mask,
                                                     const float* __restrict__ start,
                                                     const float* __restrict__ endw,
                                                     const float* __restrict__ trans,
                                                     float* __restrict__ pred) {
  const int b = blockIdx.x;
  const int c = threadIdx.x;
  __shared__ float sc[T];
  __shared__ float tr[T][T];
  __shared__ int hist[S - 1][T];
  for (int i = c; i < T * T; i += 64) tr[i / T][i % T] = trans[i];
  if (c < T) sc[c] = start[c] + em[(size_t)b * S * T + c];
  __syncthreads();
  for (int s = 1; s < S; ++s) {
    float bestv = -1e30f;
    int bestp = 0;
    if (c < T) {
      for (int p = 0; p < T; ++p) {
        float v = sc[p] + tr[p][c];
        if (v > bestv) { bestv = v; bestp = p; }
      }
      hist[s - 1][c] = bestp;
    }
    __syncthreads();
    if (c < T) {
      float m = (float)mask[b * S + s];
      sc[c] = (m > 0.f) ? (bestv + em[((size_t)b * S + s) * T + c]) : sc[c];
    }
    __syncthreads();
  }
  if (c == 0) {
    float bv = -1e30f;
    int last = 0;
    for (int p = 0; p < T; ++p) {
      float v = sc[p] + endw[p];
      if (v > bv) { bv = v; last = p; }
    }
    pred[b * S + (S - 1)] = (float)last;
    int t = last;
    for (int hs = S - 2; hs >= 0; --hs) {
      if (mask[b * S + hs + 1] > 0) t = hist[hs][t];
      pred[b * S + hs] = (float)t;
    }
  }
}

}  // namespace

extern "C" void kernel_launch(void* const* d_in, const int* in_sizes, int n_in,
                              void* d_out, int out_size, void* d_ws, size_t ws_size,
                              hipStream_t stream) {
  (void)in_sizes; (void)n_in; (void)out_size; (void)ws_size;
  const int* input_ids = (const int*)d_in[0];
  const int* attn_mask = (const int*)d_in[1];
  const int* label = (const int*)d_in[2];
  const float* word_emb = (const float*)d_in[3];
  const float* pos_emb = (const float*)d_in[4];
  const float* tok_emb = (const float*)d_in[5];
  const float* eg = (const float*)d_in[6];
  const float* ebt = (const float*)d_in[7];
  const float* Wqkv = (const float*)d_in[8];
  const float* bqkv = (const float*)d_in[9];
  const float* Wo = (const float*)d_in[10];
  const float* bo = (const float*)d_in[11];
  const float* ln1g = (const float*)d_in[12];
  const float* ln1b = (const float*)d_in[13];
  const float* W1 = (const float*)d_in[14];
  const float* b1 = (const float*)d_in[15];
  const float* W2 = (const float*)d_in[16];
  const float* b2 = (const float*)d_in[17];
  const float* ln2g = (const float*)d_in[18];
  const float* ln2b = (const float*)d_in[19];
  const float* fc_w = (const float*)d_in[20];
  const float* fc_b = (const float*)d_in[21];
  const float* crf_start = (const float*)d_in[22];
  const float* crf_end = (const float*)d_in[23];
  const float* crf_trans = (const float*)d_in[24];
  float* out = (float*)d_out;

  // ---- workspace layout (~231 MB, proven footprint) ----
  char* p = (char*)d_ws;
  ushort* xhl = (ushort*)p;    p += (size_t)BS * 2 * H * 2;      // planar residual [BS][1536]
  ushort* wQ = (ushort*)p;     p += (size_t)3 * H * 2 * H * 2;   // [2304][1536]
  ushort* wO = (ushort*)p;     p += (size_t)H * 2 * H * 2;       // [768][1536]
  ushort* wF1 = (ushort*)p;    p += (size_t)F * 2 * H * 2;       // [3072][1536]
  ushort* wF2 = (ushort*)p;    p += (size_t)H * 2 * F * 2;       // [768][6144]
  char* big = p;               p += (size_t)BS * 3 * H * 4;      // 151 MB
  float* logits = (float*)p;   p += (size_t)BS * T * 4;
  float* llh = (float*)p;      p += (size_t)B * 4;
  ushort* qkvP = (ushort*)big;             // [BS][4608] planar; attn out -> Q slot
  float* qf = (float*)big;                 // f32 row view [BS][2304]; Wo partial in K slot
  ushort* hU = (ushort*)big;               // [RC][6144] planar (FFN phase)
  float* pf = (float*)(big + (size_t)RC * F * 4);  // [2][RC][H] fp32 FFN2 partials

  embed_ln_kernel<<<BS, 256, 0, stream>>>(input_ids, word_emb, pos_emb, tok_emb, eg, ebt, xhl);

  for (int l = 0; l < L; ++l) {
    const float* wqkv_l = Wqkv + (size_t)l * H * 3 * H;
    const float* bqkv_l = bqkv + (size_t)l * 3 * H;
    const float* wo_l = Wo + (size_t)l * H * H;
    const float* bo_l = bo + (size_t)l * H;
    const float* g1 = ln1g + (size_t)l * H;
    const float* be1 = ln1b + (size_t)l * H;
    const float* w1_l = W1 + (size_t)l * H * F;
    const float* b1_l = b1 + (size_t)l * F;
    const float* w2_l = W2 + (size_t)l * F * H;
    const float* b2_l = b2 + (size_t)l * H;
    const float* g2 = ln2g + (size_t)l * H;
    const float* be2 = ln2b + (size_t)l * H;

    // all 4 weight conversions in ONE launch (6912 blocks)
    convert_all_w<<<6912, 256, 0, stream>>>(wqkv_l, wo_l, w1_l, w2_l, wQ, wO, wF1, wF2);

    // ---- attention block ----
    // QKV: [BS,H] @ [H,3H] -> qkvP planar.  grid 18x128 = 2304
    gemm_mfma<2><<<dim3(3 * H / 128, BS / 128, 1), 256, 0, stream>>>(
        xhl, wQ, bqkv_l, nullptr, qkvP, 2 * H, 2 * H, 2 * 3 * H, 0, 0, H / 32);
    attn_kernel<<<B * NH, 256, 0, stream>>>(qkvP, attn_mask);
    // Wo: [BS,H(Q-slot)] @ [H,H] -> fp32 into dead K slot, z=1 (full K per block).
    gemm_mfma<3><<<dim3(H / 128, BS / 128, 1), 256, 0, stream>>>(
        qkvP, wO, nullptr, qf + H, nullptr, 2 * 3 * H, 2 * H, 0, 3 * H, 0, H / 32);
    add_ln_kernel<1><<<BS, 256, 0, stream>>>(xhl, qf + H, nullptr, 3 * H, bo_l, g1, be1);

    // ---- FFN block (chunked) ----
    for (int ch = 0; ch < NCH; ++ch) {
      // FFN1: [RC,H] @ [H,F] -> hU (gelu, planar).  grid 24x64 = 1536
      gemm_mfma<1><<<dim3(F / 128, RC / 128, 1), 256, 0, stream>>>(
          xhl + (size_t)ch * RC * 2 * H, wF1, b1_l, nullptr, hU, 2 * H, 2 * H, 2 * F,
          0, 0, H / 32);
      // FFN2: [RC,F] @ [F,H] -> fp32 partials pf (z=2).  grid 6x64x2 = 768
      gemm_mfma<3><<<dim3(H / 128, RC / 128, 2), 256, 0, stream>>>(
          hU, wF2, nullptr, pf, nullptr, 2 * F, 2 * F, 0, H, RC * H, F / 64);
      add_ln_kernel<2><<<RC, 256, 0, stream>>>(xhl + (size_t)ch * RC * 2 * H, pf,
                                               pf + (size_t)RC * H, H, b2_l, g2, be2);
    }
  }

  fc_kernel<<<BS, 256, 0, stream>>>(xhl, fc_w, fc_b, logits);
  crf_llh_kernel<<<B, 64, 0, stream>>>(logits, label, attn_mask, crf_start, crf_end, crf_trans, llh);
  loss_kernel<<<1, 256, 0, stream>>>(llh, out);
  viterbi_kernel<<<B, 64, 0, stream>>>(logits, attn_mask, crf_start, crf_end, crf_trans, out);
}